// Round 2
// baseline (290.543 us; speedup 1.0000x reference)
//
#include <hip/hip_runtime.h>

#define BATCH 4
#define CDIM 256
#define NDIM 4096

typedef unsigned short u16;
typedef unsigned int u32;
typedef _Float16 f16;
typedef __attribute__((ext_vector_type(8))) _Float16 half8;
typedef __attribute__((ext_vector_type(4))) float floatx4;

__device__ __forceinline__ void load_lds_128(const void* g, void* l) {
  __builtin_amdgcn_global_load_lds(
      (const __attribute__((address_space(1))) u32*)g,
      (__attribute__((address_space(3))) u32*)l, 16, 0, 0);
}

// ---------------------------------------------------------------------------
// W (f32 [C][C]) -> fp16 [C][C], rows stay contraction-contiguous.
// grid 96, block 256: 3 arrays x 65536 elems / 8 per thread.
// ---------------------------------------------------------------------------
__global__ __launch_bounds__(256) void prep_w_k(
    const float* __restrict__ wq, const float* __restrict__ wk,
    const float* __restrict__ wv, f16* __restrict__ whq,
    f16* __restrict__ whk, f16* __restrict__ whv) {
  const int gid = blockIdx.x * 256 + threadIdx.x;  // 0..24575
  const int a = gid >> 13;
  const int r = gid & 8191;
  const float* src = (a == 0) ? wq : ((a == 1) ? wk : wv);
  f16* dst = (a == 0) ? whq : ((a == 1) ? whk : whv);
  float4 v0 = *(const float4*)(src + r * 8);
  float4 v1 = *(const float4*)(src + r * 8 + 4);
  half8 h;
  h[0] = (f16)v0.x; h[1] = (f16)v0.y; h[2] = (f16)v0.z; h[3] = (f16)v0.w;
  h[4] = (f16)v1.x; h[5] = (f16)v1.y; h[6] = (f16)v1.z; h[7] = (f16)v1.w;
  *(half8*)(dst + r * 8) = h;
}

// ---------------------------------------------------------------------------
// x f32 [B][C][N] -> xt fp16 [B][N][C].  grid (N/64, C/64, 2*B), block 256.
// ---------------------------------------------------------------------------
__global__ __launch_bounds__(256) void transpose_k(
    const float* __restrict__ x1, const float* __restrict__ x2,
    f16* __restrict__ xt1, f16* __restrict__ xt2) {
  __shared__ __align__(16) float tile[64 * 68];  // stride 68 f32: 16B-aligned rows, banks spread
  const int z = blockIdx.z;
  const float* src = (z & 1) ? x2 : x1;
  f16* dst = (z & 1) ? xt2 : xt1;
  const int b = z >> 1;
  src += (size_t)b * CDIM * NDIM;
  dst += (size_t)b * NDIM * CDIM;
  const int n0 = blockIdx.x * 64, c0 = blockIdx.y * 64;
  const int t = threadIdx.x;
#pragma unroll
  for (int it = 0; it < 4; ++it) {
    int chunk = t + it * 256;          // 0..1023
    int row = chunk >> 4;              // c-local (64 rows x 16 chunks of 4 f32)
    int col4 = (chunk & 15) << 2;      // n-local
    float4 v = *(const float4*)(src + (size_t)(c0 + row) * NDIM + (n0 + col4));
    *(float4*)&tile[row * 68 + col4] = v;
  }
  __syncthreads();
#pragma unroll
  for (int it = 0; it < 2; ++it) {
    int task = t + it * 256;           // 0..511
    int nl = task >> 3;                // n-local
    int cb = (task & 7) << 3;          // c-local base (8 elems)
    half8 h;
#pragma unroll
    for (int j = 0; j < 8; ++j) h[j] = (f16)tile[(cb + j) * 68 + nl];
    *(half8*)(dst + (size_t)(n0 + nl) * CDIM + (c0 + cb)) = h;
  }
}

// ---------------------------------------------------------------------------
// Qt[b][i][c] = sum_c' Xt[b][i][c'] * W[c][c'] + bias[c]  (also Kt)
// D[m=i][n=c]; A from Xt rows, B from W rows. grid (2, 32, 2*B), block 256.
// ---------------------------------------------------------------------------
__global__ __launch_bounds__(256, 2) void proj_qk_k(
    const f16* __restrict__ xt1, const f16* __restrict__ xt2,
    const f16* __restrict__ whq, const float* __restrict__ bq,
    const f16* __restrict__ whk, const float* __restrict__ bk,
    f16* __restrict__ qt, f16* __restrict__ kt) {
  const int z = blockIdx.z;
  const int which = z & 1, b = z >> 1;
  const f16* xt = which ? xt2 : xt1;
  const f16* w = which ? whk : whq;
  const float* bias = which ? bk : bq;
  f16* outp = which ? kt : qt;
  xt += (size_t)b * NDIM * CDIM;
  outp += (size_t)b * NDIM * CDIM;
  const int c0 = blockIdx.x * 128, i0 = blockIdx.y * 128;
  const int tid = threadIdx.x;
  const int wave = tid >> 6, lane = tid & 63, l16 = lane & 15, grp = lane >> 4;
  const int wi = (wave & 1) * 64, wc = (wave >> 1) * 64;
  floatx4 acc[4][4];
#pragma unroll
  for (int mb = 0; mb < 4; ++mb)
#pragma unroll
    for (int nb = 0; nb < 4; ++nb) acc[mb][nb] = (floatx4){0.f, 0.f, 0.f, 0.f};
#pragma unroll
  for (int ks = 0; ks < 8; ++ks) {
    const int kofs = ks * 32 + grp * 8;
    half8 a[4], bb[4];
#pragma unroll
    for (int mb = 0; mb < 4; ++mb)
      a[mb] = *(const half8*)(xt + (size_t)(i0 + wi + mb * 16 + l16) * CDIM + kofs);
#pragma unroll
    for (int nb = 0; nb < 4; ++nb)
      bb[nb] = *(const half8*)(w + (size_t)(c0 + wc + nb * 16 + l16) * CDIM + kofs);
#pragma unroll
    for (int mb = 0; mb < 4; ++mb)
#pragma unroll
      for (int nb = 0; nb < 4; ++nb)
        acc[mb][nb] = __builtin_amdgcn_mfma_f32_16x16x32_f16(a[mb], bb[nb], acc[mb][nb], 0, 0, 0);
  }
#pragma unroll
  for (int nb = 0; nb < 4; ++nb) {
    const int c = c0 + wc + nb * 16 + l16;
    const float bv = bias[c];
#pragma unroll
    for (int mb = 0; mb < 4; ++mb) {
      const int ibase = i0 + wi + mb * 16 + grp * 4;
#pragma unroll
      for (int r = 0; r < 4; ++r)
        outp[(size_t)(ibase + r) * CDIM + c] = (f16)(acc[mb][nb][r] + bv);
    }
  }
}

// ---------------------------------------------------------------------------
// Vs[b][c][j] = sum_c' Wv[c][c'] * Xt2[b][j][c'] + bv[c]
// D[m=c][n=j]; A from Wv rows, B from Xt2 rows. grid (2, 32, B), block 256.
// ---------------------------------------------------------------------------
__global__ __launch_bounds__(256, 2) void proj_v_k(
    const f16* __restrict__ xt2, const f16* __restrict__ whv,
    const float* __restrict__ bv, f16* __restrict__ vsout) {
  const int b = blockIdx.z;
  const f16* xt = xt2 + (size_t)b * NDIM * CDIM;
  f16* outp = vsout + (size_t)b * CDIM * NDIM;
  const int c0 = blockIdx.x * 128, j0 = blockIdx.y * 128;
  const int tid = threadIdx.x;
  const int wave = tid >> 6, lane = tid & 63, l16 = lane & 15, grp = lane >> 4;
  const int wc = (wave & 1) * 64, wj = (wave >> 1) * 64;
  floatx4 acc[4][4];
#pragma unroll
  for (int mb = 0; mb < 4; ++mb)
#pragma unroll
    for (int nb = 0; nb < 4; ++nb) acc[mb][nb] = (floatx4){0.f, 0.f, 0.f, 0.f};
#pragma unroll
  for (int ks = 0; ks < 8; ++ks) {
    const int kofs = ks * 32 + grp * 8;
    half8 a[4], bb[4];
#pragma unroll
    for (int mb = 0; mb < 4; ++mb)
      a[mb] = *(const half8*)(whv + (size_t)(c0 + wc + mb * 16 + l16) * CDIM + kofs);
#pragma unroll
    for (int nb = 0; nb < 4; ++nb)
      bb[nb] = *(const half8*)(xt + (size_t)(j0 + wj + nb * 16 + l16) * CDIM + kofs);
#pragma unroll
    for (int mb = 0; mb < 4; ++mb)
#pragma unroll
      for (int nb = 0; nb < 4; ++nb)
        acc[mb][nb] = __builtin_amdgcn_mfma_f32_16x16x32_f16(a[mb], bb[nb], acc[mb][nb], 0, 0, 0);
  }
#pragma unroll
  for (int mb = 0; mb < 4; ++mb)
#pragma unroll
    for (int r = 0; r < 4; ++r) {
      const int c = c0 + wc + mb * 16 + grp * 4 + r;
      const float bvv = bv[c];
#pragma unroll
      for (int nb = 0; nb < 4; ++nb) {
        const int j = j0 + wj + nb * 16 + l16;
        outp[(size_t)c * NDIM + j] = (f16)(acc[mb][nb][r] + bvv);
      }
    }
}

// ---------------------------------------------------------------------------
// Flash attention, fp16 compute, f32 out. 256 blocks (XCD-swizzled), 4 waves.
// LDS: 2 x (K 32KB + V 32KB) double-buffer + P 8KB = 136 KB -> 1 block/CU.
// Prefetch is issued right after the per-iteration barrier, so the compiler's
// vmcnt(0) drain at the NEXT barrier waits on loads that had a full compute
// phase in flight.
// ---------------------------------------------------------------------------
__global__ __launch_bounds__(256) void flash_k(
    const f16* __restrict__ qt, const f16* __restrict__ kt,
    const f16* __restrict__ vs, float* __restrict__ outp) {
  __shared__ __align__(16) u16 smem[2 * 32768 + 4096];  // 136 KB
  const int bx = blockIdx.x;
  // XCD swizzle: batch pinned to XCD pairs -> per-XCD K/V working set 4 MB (fits L2)
  const int b = (bx & 7) >> 1;
  const int i0 = ((bx >> 3) + ((bx & 1) << 5)) * 64;
  const f16* Q = qt + (size_t)b * NDIM * CDIM;
  const f16* K = kt + (size_t)b * NDIM * CDIM;
  const f16* V = vs + (size_t)b * CDIM * NDIM;
  float* outg = outp + (size_t)b * CDIM * NDIM;
  const int tid = threadIdx.x;
  const int wave = tid >> 6, lane = tid & 63, l16 = lane & 15, grp = lane >> 4;

  // Q fragments resident: A[m=l16][k=ks*32+grp*8+j]
  half8 qf[8];
#pragma unroll
  for (int ks = 0; ks < 8; ++ks)
    qf[ks] = *(const half8*)(Q + (size_t)(i0 + wave * 16 + l16) * CDIM + ks * 32 + grp * 8);

  floatx4 O[16];
#pragma unroll
  for (int cb = 0; cb < 16; ++cb) O[cb] = (floatx4){0.f, 0.f, 0.f, 0.f};
  float mrow[4], lrow[4];
#pragma unroll
  for (int r = 0; r < 4; ++r) { mrow[r] = -1e30f; lrow[r] = 0.f; }

  f16* sPh = (f16*)(smem + 65536);
  f16* sPw = sPh + wave * (16 * 64);

  const int kr2 = lane >> 5, kp = lane & 31;   // K staging: 2 rows / call
  const int vr = lane >> 3, vp = lane & 7;     // V staging: 8 rows / call

#define STAGE(J0, BUF)                                                        \
  {                                                                           \
    u16* bK = (BUF);                                                          \
    u16* bV = (BUF) + 16384;                                                  \
    _Pragma("unroll") for (int it = 0; it < 8; ++it) {                        \
      const int row = wave * 16 + it * 2 + kr2;                               \
      const int g = kp ^ (row & 7);                                           \
      load_lds_128(K + (size_t)((J0) + row) * CDIM + g * 8,                   \
                   &bK[(wave * 16 + it * 2) * 256]);                          \
    }                                                                         \
    _Pragma("unroll") for (int it = 0; it < 8; ++it) {                        \
      const int c = wave * 64 + it * 8 + vr;                                  \
      const int g = vp ^ (c & 7);                                             \
      load_lds_128(V + (size_t)c * NDIM + (J0) + g * 8,                       \
                   &bV[(wave * 64 + it * 8) * 64]);                           \
    }                                                                         \
  }

  STAGE(0, smem)

  for (int t = 0; t < NDIM / 64; ++t) {
    __syncthreads();  // drains prefetch(t) (in flight during compute of t-1)
    if (t + 1 < NDIM / 64) STAGE((t + 1) * 64, smem + ((t + 1) & 1) * 32768)
    u16* bK = smem + (t & 1) * 32768;
    u16* bV = bK + 16384;

    // ---- S = Q K^T : 4 independent accumulation chains ----
    floatx4 S4[4];
#pragma unroll
    for (int jb = 0; jb < 4; ++jb) S4[jb] = (floatx4){0.f, 0.f, 0.f, 0.f};
#pragma unroll
    for (int ks = 0; ks < 8; ++ks) {
      const int chunk = ks * 4 + grp;
#pragma unroll
      for (int jb = 0; jb < 4; ++jb) {
        const int row = jb * 16 + l16;
        half8 kf = *(const half8*)&bK[row * 256 + ((chunk ^ (row & 7)) << 3)];
        S4[jb] = __builtin_amdgcn_mfma_f32_16x16x32_f16(qf[ks], kf, S4[jb], 0, 0, 0);
      }
    }

    // ---- online softmax: lane holds rows grp*4+r, col jb*16+l16 ----
    float mnew[4];
#pragma unroll
    for (int r = 0; r < 4; ++r)
      mnew[r] = fmaxf(fmaxf(S4[0][r], S4[1][r]), fmaxf(S4[2][r], S4[3][r]));
#pragma unroll
    for (int mask = 1; mask < 16; mask <<= 1)
#pragma unroll
      for (int r = 0; r < 4; ++r)
        mnew[r] = fmaxf(mnew[r], __shfl_xor(mnew[r], mask, 64));
    float alpha[4];
#pragma unroll
    for (int r = 0; r < 4; ++r) {
      const float mt = fmaxf(mrow[r], mnew[r]);
      alpha[r] = __expf(mrow[r] - mt);
      mrow[r] = mt;
    }
    float rsum[4];
#pragma unroll
    for (int r = 0; r < 4; ++r) {
#pragma unroll
      for (int jb = 0; jb < 4; ++jb) S4[jb][r] = __expf(S4[jb][r] - mrow[r]);
      rsum[r] = (S4[0][r] + S4[1][r]) + (S4[2][r] + S4[3][r]);
    }
#pragma unroll
    for (int mask = 1; mask < 16; mask <<= 1)
#pragma unroll
      for (int r = 0; r < 4; ++r)
        rsum[r] += __shfl_xor(rsum[r], mask, 64);
#pragma unroll
    for (int r = 0; r < 4; ++r) lrow[r] = lrow[r] * alpha[r] + rsum[r];
#pragma unroll
    for (int cb = 0; cb < 16; ++cb)
#pragma unroll
      for (int r = 0; r < 4; ++r) O[cb][r] *= alpha[r];

    // ---- P: C/D layout -> A-operand layout via per-wave LDS ----
#pragma unroll
    for (int jb = 0; jb < 4; ++jb)
#pragma unroll
      for (int r = 0; r < 4; ++r) {
        const int row = grp * 4 + r;
        const int col = jb * 16 + l16;
        sPw[row * 64 + (((col >> 3) ^ (row & 7)) << 3) + (col & 7)] = (f16)S4[jb][r];
      }
    half8 pa[2];
#pragma unroll
    for (int ks = 0; ks < 2; ++ks) {
      const int chunk = ks * 4 + grp;
      pa[ks] = *(const half8*)&sPw[l16 * 64 + ((chunk ^ (l16 & 7)) << 3)];
    }

    // ---- O += P V : 16 independent chains ----
#pragma unroll
    for (int ks = 0; ks < 2; ++ks) {
      const int chunk = ks * 4 + grp;
#pragma unroll
      for (int cb = 0; cb < 16; ++cb) {
        const int c = cb * 16 + l16;
        half8 vf = *(const half8*)&bV[c * 64 + ((chunk ^ (c & 7)) << 3)];
        O[cb] = __builtin_amdgcn_mfma_f32_16x16x32_f16(pa[ks], vf, O[cb], 0, 0, 0);
      }
    }
  }
  __syncthreads();  // all waves done with smem buffers

  // ---- epilogue: out[c][i0+i] = O[i][c]/l[i], f32, via LDS transpose ----
  float inv[4];
#pragma unroll
  for (int r = 0; r < 4; ++r) inv[r] = 1.0f / lrow[r];
  float* sO = (float*)smem;  // 256 x 68 f32 = 68 KB <= 136 KB
#pragma unroll
  for (int cb = 0; cb < 16; ++cb) {
    const int c = cb * 16 + l16;
#pragma unroll
    for (int r = 0; r < 4; ++r)
      sO[c * 68 + wave * 16 + grp * 4 + r] = O[cb][r] * inv[r];
  }
  __syncthreads();
#pragma unroll
  for (int it = 0; it < 16; ++it) {
    const int idx = tid + it * 256;    // 0..4095
    const int c = idx >> 4, p = idx & 15;
    float4 v = *(const float4*)&sO[c * 68 + p * 4];
    *(float4*)(outg + (size_t)c * NDIM + i0 + p * 4) = v;
  }
}

// ---------------------------------------------------------------------------
extern "C" void kernel_launch(void* const* d_in, const int* in_sizes, int n_in,
                              void* d_out, int out_size, void* d_ws, size_t ws_size,
                              hipStream_t stream) {
  const float* x1 = (const float*)d_in[0];
  const float* x2 = (const float*)d_in[1];
  const float* Wq = (const float*)d_in[2];
  const float* bq = (const float*)d_in[3];
  const float* Wk = (const float*)d_in[4];
  const float* bk = (const float*)d_in[5];
  const float* Wv = (const float*)d_in[6];
  const float* bv = (const float*)d_in[7];
  float* out = (float*)d_out;
  char* ws = (char*)d_ws;
  const size_t SZ = (size_t)BATCH * NDIM * CDIM * sizeof(f16);  // 8 MB each
  f16* xt1 = (f16*)(ws + 0 * SZ);
  f16* xt2 = (f16*)(ws + 1 * SZ);
  f16* qt  = (f16*)(ws + 2 * SZ);
  f16* kt  = (f16*)(ws + 3 * SZ);
  f16* vsp = (f16*)(ws + 4 * SZ);
  f16* whq = (f16*)(ws + 5 * SZ);
  f16* whk = whq + CDIM * CDIM;
  f16* whv = whk + CDIM * CDIM;

  prep_w_k<<<dim3(96), dim3(256), 0, stream>>>(Wq, Wk, Wv, whq, whk, whv);
  transpose_k<<<dim3(NDIM / 64, CDIM / 64, 2 * BATCH), dim3(256), 0, stream>>>(x1, x2, xt1, xt2);
  proj_qk_k<<<dim3(2, 32, 2 * BATCH), dim3(256), 0, stream>>>(xt1, xt2, whq, bq, whk, bk, qt, kt);
  proj_v_k<<<dim3(2, 32, BATCH), dim3(256), 0, stream>>>(xt2, whv, bv, vsp);
  flash_k<<<dim3(256), dim3(256), 0, stream>>>(qt, kt, vsp, out);
}